// Round 1
// baseline (4618.766 us; speedup 1.0000x reference)
//
#include <hip/hip_runtime.h>
#include <hip/hip_bf16.h>
#include <math.h>

// Problem dims
#define NB 32
#define NS 128
#define NT 64
#define NV 32000
#define NE 256
#define NH 512

typedef short s16x8 __attribute__((ext_vector_type(8)));
typedef float f32x4 __attribute__((ext_vector_type(4)));

__device__ __forceinline__ unsigned short f2bf(float x) {
    union { float f; unsigned u; } v; v.f = x;
    unsigned r = v.u + 0x7FFFu + ((v.u >> 16) & 1u);   // RNE
    return (unsigned short)(r >> 16);
}

// ---------------------------------------------------------------------------
// K0: pack W_s = [W_prev | Wh_g[:, :512] | Wh]  (512 x 1536) into MFMA
// B-fragment order: tile (ct,kt) holds B[k][c] for c=ct*16+(lane&15),
// k=kt*32+(lane>>4)*8+j  -> one coalesced 16B load per lane per MFMA in scan.
// ---------------------------------------------------------------------------
__global__ void build_wfrag_k(const float* __restrict__ Wp,
                              const float* __restrict__ Whg,
                              const float* __restrict__ Wh,
                              unsigned short* __restrict__ wfrag) {
    int blk = blockIdx.x;            // = ct*16 + kt ; ct<96, kt<16
    int lane = threadIdx.x;
    int ct = blk >> 4, kt = blk & 15;
    int c = ct * 16 + (lane & 15);
    int kb = kt * 32 + (lane >> 4) * 8;
    s16x8 v;
#pragma unroll
    for (int j = 0; j < 8; ++j) {
        int k = kb + j;
        float x;
        if (c < 512)       x = Wp[k * 512 + c];
        else if (c < 1024) x = Whg[k * 1024 + (c - 512)];
        else               x = Wh[k * 512 + (c - 1024)];
        v[j] = (short)f2bf(x);
    }
    ((s16x8*)wfrag)[blk * 64 + lane] = v;
}

// ---------------------------------------------------------------------------
// Generic MFMA bf16 GEMM, 128x128 tile, BK=32, 4 waves (each 64x64 = 4x4 frags)
// MODE 0 (PRE): A=hiddens f32 [4096][1024]; B packed {W_enc|Wc_g[:, :512]|Wc};
//               epilogue routes cols: [0,512)->Ta=tanh(v+b_enc), [512,1024)->hWcg, rest->hWc
// MODE 1 (XP):  A=embed rows gathered by target [2048][256]; B={Wi_g[:, :512]|Wi};
//               epilogue adds summed gate biases; out xgxs [2048][1024]
// MODE 2 (OUT): A=dh bf16 [2048][512]; B=W_out [512][32000]; out = v + 1.5*b_out
// ---------------------------------------------------------------------------
template<int MODE>
__global__ __launch_bounds__(256, 2) void gemm_mfma(
    const float* __restrict__ Af, const unsigned short* __restrict__ Abf,
    const int* __restrict__ gidx,
    const float* __restrict__ B0, const float* __restrict__ B1, const float* __restrict__ B2,
    const float* __restrict__ e0, const float* __restrict__ e1, const float* __restrict__ e2,
    const float* __restrict__ e3, const float* __restrict__ e4, const float* __restrict__ e5,
    float* __restrict__ O0, float* __restrict__ O1, float* __restrict__ O2)
{
    constexpr int M   = (MODE == 0) ? 4096 : 2048;
    constexpr int K   = (MODE == 0) ? 1024 : ((MODE == 1) ? 256 : 512);
    constexpr int LDA = (MODE == 0) ? 1024 : ((MODE == 1) ? 256 : 512);
    constexpr int MB  = M / 128;

    const int bm = blockIdx.x % MB, bn = blockIdx.x / MB;
    const int m0 = bm * 128, n0 = bn * 128;

    // B descriptor (per-block constant; 128-col tiles never straddle submatrices)
    const float* Bp; int ldb, coff;
    if constexpr (MODE == 0) {
        int sub = n0 >> 9;
        Bp   = (sub == 0) ? B0 : (sub == 1) ? B1 : B2;
        ldb  = (sub == 1) ? 1024 : 512;
        coff = n0 & 511;
    } else if constexpr (MODE == 1) {
        if (n0 < 512) { Bp = B0; ldb = 1024; coff = n0; }
        else          { Bp = B1; ldb = 512;  coff = n0 - 512; }
    } else {
        Bp = B0; ldb = 32000; coff = n0;
    }

    __shared__ unsigned short As[128 * 40];   // [row][k] padded to 40 (2-way banks)
    __shared__ unsigned short Bs[128 * 40];   // [col][k] padded

    const int tid = threadIdx.x, lane = tid & 63, w = tid >> 6;
    const int wr = w >> 1, wc = w & 1;
    const int k0f = (lane >> 4) * 8;
    const int rsel = lane & 15;

    f32x4 acc[4][4];
#pragma unroll
    for (int i = 0; i < 4; ++i)
#pragma unroll
        for (int j = 0; j < 4; ++j) { f32x4 z = {0.f, 0.f, 0.f, 0.f}; acc[i][j] = z; }

    for (int kt = 0; kt < K / 32; ++kt) {
        const int k0 = kt * 32;
        __syncthreads();
        // stage A tile 128x32
#pragma unroll
        for (int i = 0; i < 16; ++i) {
            int idx = tid + i * 256;
            int r = idx >> 5, k = idx & 31;
            unsigned short v;
            if constexpr (MODE == 2) {
                v = Abf[(size_t)(m0 + r) * LDA + k0 + k];
            } else if constexpr (MODE == 1) {
                int g = gidx[m0 + r];
                v = f2bf(Af[(size_t)g * 256 + k0 + k]);
            } else {
                v = f2bf(Af[(size_t)(m0 + r) * LDA + k0 + k]);
            }
            As[r * 40 + k] = v;
        }
        // stage B tile 32x128 (stored transposed [c][k])
#pragma unroll
        for (int i = 0; i < 16; ++i) {
            int idx = tid + i * 256;
            int k = idx >> 7, c = idx & 127;
            Bs[c * 40 + k] = f2bf(Bp[(size_t)(k0 + k) * ldb + coff + c]);
        }
        __syncthreads();

        s16x8 af[4], bf[4];
#pragma unroll
        for (int i = 0; i < 4; ++i)
            af[i] = *(const s16x8*)&As[(wr * 64 + i * 16 + rsel) * 40 + k0f];
#pragma unroll
        for (int j = 0; j < 4; ++j)
            bf[j] = *(const s16x8*)&Bs[(wc * 64 + j * 16 + rsel) * 40 + k0f];
#pragma unroll
        for (int i = 0; i < 4; ++i)
#pragma unroll
            for (int j = 0; j < 4; ++j)
                acc[i][j] = __builtin_amdgcn_mfma_f32_16x16x32_bf16(af[i], bf[j], acc[i][j], 0, 0, 0);
    }

    // epilogue: row=(lane>>4)*4+reg, col=lane&15 within each 16x16 frag (m89-verified)
    const int rg = (lane >> 4) * 4;
#pragma unroll
    for (int i = 0; i < 4; ++i)
#pragma unroll
        for (int j = 0; j < 4; ++j)
#pragma unroll
            for (int r = 0; r < 4; ++r) {
                int row = m0 + wr * 64 + i * 16 + rg + r;
                int col = n0 + wc * 64 + j * 16 + rsel;
                float v = acc[i][j][r];
                if constexpr (MODE == 0) {
                    int sub = col >> 9, c = col & 511;
                    if (sub == 0)      O0[(size_t)row * 512 + c] = tanhf(v + e0[c]);
                    else if (sub == 1) O1[(size_t)row * 512 + c] = v;
                    else               O2[(size_t)row * 512 + c] = v;
                } else if constexpr (MODE == 1) {
                    float bias;
                    if (col < 512) bias = e0[col] + e1[col] + e2[col];
                    else { int h = col - 512; bias = e3[h] + e4[h] + e5[h]; }
                    O0[(size_t)row * 1024 + col] = v + bias;
                } else {
                    O0[(size_t)row * 32000 + col] = v + 1.5f * e0[col];
                }
            }
}

// ---------------------------------------------------------------------------
// K3: sequential scan. 1 block per batch element, 1024 threads (16 waves).
// State s in LDS (f32 + bf16 copy). Per step:
//  P1 u = s @ [W_prev|Wh_g'|Wh] via M=1 MFMA (rows replicated)  -> qu,gu,su
//  P2 tq = tanh(qu)   P3 scores via tanh-addition identity on precomputed Ta
//  P4 softmax (wave0) P5 ctxg/ctxs = alpha @ {hWcg,hWc}         P6 gate+update
// ---------------------------------------------------------------------------
__global__ __launch_bounds__(1024) void scan_kernel(
    const float* __restrict__ content, const float* __restrict__ sentiment,
    const float* __restrict__ b_prev,  const float* __restrict__ W_att,
    const float* __restrict__ Ta, const float* __restrict__ hWcg,
    const float* __restrict__ hWc, const float* __restrict__ xgxs,
    const unsigned short* __restrict__ wfrag, unsigned short* __restrict__ dh)
{
    const int b = blockIdx.x;
    const int tid = threadIdx.x, lane = tid & 63, w = tid >> 6;

    __shared__ float s_f[512];
    __shared__ unsigned short s_b[512];
    __shared__ float tq[512];
    __shared__ float qu[512], gu[512], su[512];
    __shared__ float sc[128], al[128];
    __shared__ float cg[512], cs[512];

    if (tid < 512) {
        float v = content[b * 512 + tid];
        s_f[tid] = v; s_b[tid] = f2bf(v);
    }
    // hoisted per-lane constants
    float wv[8];
    {
        const f32x4* wa = (const f32x4*)&W_att[lane * 8];
        f32x4 a0 = wa[0], a1 = wa[1];
#pragma unroll
        for (int j = 0; j < 4; ++j) { wv[j] = a0[j]; wv[4 + j] = a1[j]; }
    }
    float senth = 0.f, bprev_h = 0.f;
    if (tid < 512) { senth = 0.5f * sentiment[b * 512 + tid]; bprev_h = b_prev[tid]; }
    const int k0f = (lane >> 4) * 8;
    __syncthreads();

    for (int t = 0; t < 64; ++t) {
        // ---- P1: u = s @ W_s (1536 cols) ----
        {
            f32x4 a6[6];
#pragma unroll
            for (int ci = 0; ci < 6; ++ci) { f32x4 z = {0.f,0.f,0.f,0.f}; a6[ci] = z; }
            const s16x8* wf = (const s16x8*)wfrag;
            for (int kt = 0; kt < 16; ++kt) {
                s16x8 a = *(const s16x8*)&s_b[kt * 32 + k0f];
#pragma unroll
                for (int ci = 0; ci < 6; ++ci) {
                    int ctile = w * 6 + ci;
                    s16x8 bfr = wf[(ctile * 16 + kt) * 64 + lane];
                    a6[ci] = __builtin_amdgcn_mfma_f32_16x16x32_bf16(a, bfr, a6[ci], 0, 0, 0);
                }
            }
            if (lane < 16) {
#pragma unroll
                for (int ci = 0; ci < 6; ++ci) {
                    int c = (w * 6 + ci) * 16 + lane;
                    float v = a6[ci][0];                 // row 0 (rows replicated)
                    if (c < 512)       qu[c] = v;        // b_prev added in P2
                    else if (c < 1024) gu[c - 512] = v;
                    else               su[c - 1024] = v;
                }
            }
        }
        __syncthreads();
        // ---- P2: tq = tanh(q) ----
        if (tid < 512) tq[tid] = tanhf(qu[tid] + bprev_h);
        __syncthreads();
        // ---- P3: scores via tanh(a+q) = (Ta+tq)/(1+Ta*tq) ----
        {
            float tqv[8];
            {
                const f32x4* tp = (const f32x4*)&tq[lane * 8];
                f32x4 t0 = tp[0], t1 = tp[1];
#pragma unroll
                for (int j = 0; j < 4; ++j) { tqv[j] = t0[j]; tqv[4 + j] = t1[j]; }
            }
#pragma unroll
            for (int s8 = 0; s8 < 8; ++s8) {
                int s = w * 8 + s8;
                const f32x4* tr = (const f32x4*)&Ta[((size_t)(b * 128 + s)) * 512 + lane * 8];
                f32x4 q0 = tr[0], q1 = tr[1];
                float a = 0.f;
#pragma unroll
                for (int j = 0; j < 8; ++j) {
                    float ta = (j < 4) ? q0[j] : q1[j - 4];
                    float num = ta + tqv[j];
                    float den = fmaf(ta, tqv[j], 1.0f);
                    a = fmaf(wv[j], num * __builtin_amdgcn_rcpf(den), a);
                }
#pragma unroll
                for (int off = 32; off; off >>= 1) a += __shfl_xor(a, off, 64);
                if (lane == 0) sc[s] = a;
            }
        }
        __syncthreads();
        // ---- P4: softmax over 128 (wave 0) ----
        if (w == 0) {
            float v0 = sc[lane], v1 = sc[lane + 64];
            float m = fmaxf(v0, v1);
#pragma unroll
            for (int off = 32; off; off >>= 1) m = fmaxf(m, __shfl_xor(m, off, 64));
            float p0 = __expf(v0 - m), p1 = __expf(v1 - m);
            float sm = p0 + p1;
#pragma unroll
            for (int off = 32; off; off >>= 1) sm += __shfl_xor(sm, off, 64);
            float inv = __builtin_amdgcn_rcpf(sm);
            al[lane] = p0 * inv; al[lane + 64] = p1 * inv;
        }
        __syncthreads();
        // ---- P5: ctx projections ----
        {
            int mat = tid >> 9, h = tid & 511;
            const float* Mp = (mat ? hWc : hWcg) + ((size_t)b * 128) * 512 + h;
            float a0 = 0.f, a1 = 0.f, a2 = 0.f, a3 = 0.f;
#pragma unroll 4
            for (int s = 0; s < 128; s += 4) {
                a0 = fmaf(al[s + 0], Mp[(size_t)(s + 0) * 512], a0);
                a1 = fmaf(al[s + 1], Mp[(size_t)(s + 1) * 512], a1);
                a2 = fmaf(al[s + 2], Mp[(size_t)(s + 2) * 512], a2);
                a3 = fmaf(al[s + 3], Mp[(size_t)(s + 3) * 512], a3);
            }
            float a = (a0 + a1) + (a2 + a3);
            if (mat) cs[h] = a; else cg[h] = a;
        }
        __syncthreads();
        // ---- P6: gate + state update ----
        if (tid < 512) {
            int h = tid;
            size_t row = (size_t)b * 64 + t;
            float g  = gu[h] + xgxs[row * 1024 + h] + cg[h];
            float r  = __builtin_amdgcn_rcpf(1.0f + __expf(-g));
            float sp = su[h] + xgxs[row * 1024 + 512 + h] + cs[h];
            float e  = __expf(2.0f * sp);
            float st = 1.0f - 2.0f * __builtin_amdgcn_rcpf(e + 1.0f);
            float sold = s_f[h];
            float ns = sold + r * (st - sold);
            s_f[h] = ns;
            s_b[h] = f2bf(ns);
            dh[row * 512 + h] = f2bf(ns + senth);   // Dh' = new_s + 0.5*sentiment
        }
        __syncthreads();
    }
}

// ---------------------------------------------------------------------------
extern "C" void kernel_launch(void* const* d_in, const int* in_sizes, int n_in,
                              void* d_out, int out_size, void* d_ws, size_t ws_size,
                              hipStream_t stream) {
    const float* content  = (const float*)d_in[0];
    const float* sentiment= (const float*)d_in[1];
    const float* hiddens  = (const float*)d_in[2];
    const int*   target   = (const int*)  d_in[3];
    const float* embed    = (const float*)d_in[4];
    const float* W_enc = (const float*)d_in[5];  const float* b_enc = (const float*)d_in[6];
    const float* W_prev= (const float*)d_in[7];  const float* b_prev= (const float*)d_in[8];
    const float* W_att = (const float*)d_in[9];  /* b_att (d_in[10]) cancels in softmax */
    const float* Wi_g  = (const float*)d_in[11]; const float* bi_g  = (const float*)d_in[12];
    const float* Wh_g  = (const float*)d_in[13]; const float* bh_g  = (const float*)d_in[14];
    const float* Wc_g  = (const float*)d_in[15]; const float* bc_g  = (const float*)d_in[16];
    const float* Wi    = (const float*)d_in[17]; const float* bi    = (const float*)d_in[18];
    const float* Wh    = (const float*)d_in[19]; const float* bh    = (const float*)d_in[20];
    const float* Wc    = (const float*)d_in[21]; const float* bc    = (const float*)d_in[22];
    const float* W_out = (const float*)d_in[23]; const float* b_out = (const float*)d_in[24];
    float* out = (float*)d_out;

    // workspace layout
    char* ws = (char*)d_ws;
    unsigned short* wfrag = (unsigned short*)ws;                 // 96*16*64*8*2 = 1.5 MB
    float* Ta   = (float*)(ws + (1u << 21));                     // 8 MB  [4096][512]
    float* hWcg = Ta   + (size_t)4096 * 512;                     // 8 MB
    float* hWc  = hWcg + (size_t)4096 * 512;                     // 8 MB
    float* xgxs = hWc  + (size_t)4096 * 512;                     // 8 MB  [2048][1024]
    unsigned short* dh = (unsigned short*)(xgxs + (size_t)2048 * 1024); // 2 MB [2048][512]

    // K0: pack recurrent weight fragments
    build_wfrag_k<<<96 * 16, 64, 0, stream>>>(W_prev, Wh_g, Wh, wfrag);

    // K1: PRE gemm -> Ta (tanh(enc_proj+b_enc)), hWcg, hWc
    gemm_mfma<0><<<32 * 12, 256, 0, stream>>>(
        hiddens, nullptr, nullptr, W_enc, Wc_g, Wc,
        b_enc, nullptr, nullptr, nullptr, nullptr, nullptr,
        Ta, hWcg, hWc);

    // K2: XP gemm -> xgxs = [emb@Wi_g' + (bi_g+bh_g+bc_g)' | emb@Wi + (bi+bh+bc)]
    gemm_mfma<1><<<16 * 8, 256, 0, stream>>>(
        embed, nullptr, target, Wi_g, Wi, nullptr,
        bi_g, bh_g, bc_g, bi, bh, bc,
        xgxs, nullptr, nullptr);

    // K3: sequential scan -> dh (bf16, sentiment folded)
    scan_kernel<<<NB, 1024, 0, stream>>>(
        content, sentiment, b_prev, W_att, Ta, hWcg, hWc, xgxs, wfrag, dh);

    // K4: OUT gemm -> d_out = dh@W_out + 1.5*b_out
    gemm_mfma<2><<<16 * 250, 256, 0, stream>>>(
        nullptr, dh, nullptr, W_out, nullptr, nullptr,
        b_out, nullptr, nullptr, nullptr, nullptr, nullptr,
        out, nullptr, nullptr);

    (void)in_sizes; (void)n_in; (void)out_size; (void)ws_size;
}

// Round 2
// 3416.759 us; speedup vs baseline: 1.3518x; 1.3518x over previous
//
#include <hip/hip_runtime.h>
#include <hip/hip_bf16.h>
#include <math.h>

// Problem dims
#define NB 32
#define NS 128
#define NT 64
#define NV 32000
#define NE 256
#define NH 512

typedef short s16x8 __attribute__((ext_vector_type(8)));
typedef float f32x4 __attribute__((ext_vector_type(4)));

__device__ __forceinline__ unsigned short f2bf(float x) {
    union { float f; unsigned u; } v; v.f = x;
    unsigned r = v.u + 0x7FFFu + ((v.u >> 16) & 1u);   // RNE
    return (unsigned short)(r >> 16);
}
__device__ __forceinline__ float bf2f(short h) {
    union { unsigned u; float f; } x;
    x.u = ((unsigned)(unsigned short)h) << 16;
    return x.f;
}

// ---------------------------------------------------------------------------
// Global barrier among 32 persistent blocks. Counters in d_ws, memset to 0
// per launch. tid0 arrives + spins; fences give agent-scope release/acquire.
// ---------------------------------------------------------------------------
__device__ __forceinline__ void gbar(unsigned* c, int idx, unsigned nb) {
    __threadfence();                 // release my block's global writes
    __syncthreads();
    if (threadIdx.x == 0) {
        __hip_atomic_fetch_add(&c[idx], 1u, __ATOMIC_ACQ_REL, __HIP_MEMORY_SCOPE_AGENT);
        while (__hip_atomic_load(&c[idx], __ATOMIC_ACQUIRE, __HIP_MEMORY_SCOPE_AGENT) < nb)
            __builtin_amdgcn_s_sleep(2);
    }
    __syncthreads();
    __builtin_amdgcn_fence(__ATOMIC_ACQUIRE, "agent");  // all threads see released writes
}

// ---------------------------------------------------------------------------
// K0: pack W_s = [W_prev | Wh_g[:, :512] | Wh]  (512 x 1536) into MFMA
// B-fragment order: tile (ct,kt) holds B[k][c] for c=ct*16+(lane&15),
// k=kt*32+(lane>>4)*8+j.
// ---------------------------------------------------------------------------
__global__ void build_wfrag_k(const float* __restrict__ Wp,
                              const float* __restrict__ Whg,
                              const float* __restrict__ Wh,
                              unsigned short* __restrict__ wfrag) {
    int blk = blockIdx.x;            // = ct*16 + kt ; ct<96, kt<16
    int lane = threadIdx.x;
    int ct = blk >> 4, kt = blk & 15;
    int c = ct * 16 + (lane & 15);
    int kb = kt * 32 + (lane >> 4) * 8;
    s16x8 v;
#pragma unroll
    for (int j = 0; j < 8; ++j) {
        int k = kb + j;
        float x;
        if (c < 512)       x = Wp[k * 512 + c];
        else if (c < 1024) x = Whg[k * 1024 + (c - 512)];
        else               x = Wh[k * 512 + (c - 1024)];
        v[j] = (short)f2bf(x);
    }
    ((s16x8*)wfrag)[blk * 64 + lane] = v;
}

// ---------------------------------------------------------------------------
// Generic MFMA bf16 GEMM, 128x128 tile, BK=32, 4 waves (each 64x64 = 4x4 frags)
// MODE 0 (PRE): A=hiddens f32 [4096][1024]; B packed {W_enc|Wc_g[:, :512]|Wc};
//   epilogue: cols [0,512)->Ta_bf16[s][h]=tanh(v+b_enc); [512,1024)->hWcg_t
//   bf16 TRANSPOSED [b][h][s]; rest->hWc_t (same transposed layout).
// MODE 1 (XP):  A=embed rows gathered by target [2048][256]; B={Wi_g[:, :512]|Wi};
//   epilogue adds summed gate biases; out xgxs f32 [2048][1024]
// MODE 2 (OUT): A=dh bf16 [2048][512]; B=W_out [512][32000]; out = v + 1.5*b_out
// ---------------------------------------------------------------------------
template<int MODE>
__global__ __launch_bounds__(256, 2) void gemm_mfma(
    const float* __restrict__ Af, const unsigned short* __restrict__ Abf,
    const int* __restrict__ gidx,
    const float* __restrict__ B0, const float* __restrict__ B1, const float* __restrict__ B2,
    const float* __restrict__ e0, const float* __restrict__ e1, const float* __restrict__ e2,
    const float* __restrict__ e3, const float* __restrict__ e4, const float* __restrict__ e5,
    void* __restrict__ O0v, void* __restrict__ O1v, void* __restrict__ O2v)
{
    constexpr int M   = (MODE == 0) ? 4096 : 2048;
    constexpr int K   = (MODE == 0) ? 1024 : ((MODE == 1) ? 256 : 512);
    constexpr int LDA = (MODE == 0) ? 1024 : ((MODE == 1) ? 256 : 512);
    constexpr int MB  = M / 128;

    const int bm = blockIdx.x % MB, bn = blockIdx.x / MB;
    const int m0 = bm * 128, n0 = bn * 128;

    const float* Bp; int ldb, coff;
    if constexpr (MODE == 0) {
        int sub = n0 >> 9;
        Bp   = (sub == 0) ? B0 : (sub == 1) ? B1 : B2;
        ldb  = (sub == 1) ? 1024 : 512;
        coff = n0 & 511;
    } else if constexpr (MODE == 1) {
        if (n0 < 512) { Bp = B0; ldb = 1024; coff = n0; }
        else          { Bp = B1; ldb = 512;  coff = n0 - 512; }
    } else {
        Bp = B0; ldb = 32000; coff = n0;
    }

    __shared__ unsigned short As[128 * 40];
    __shared__ unsigned short Bs[128 * 40];

    const int tid = threadIdx.x, lane = tid & 63, w = tid >> 6;
    const int wr = w >> 1, wc = w & 1;
    const int k0f = (lane >> 4) * 8;
    const int rsel = lane & 15;

    f32x4 acc[4][4];
#pragma unroll
    for (int i = 0; i < 4; ++i)
#pragma unroll
        for (int j = 0; j < 4; ++j) { f32x4 z = {0.f, 0.f, 0.f, 0.f}; acc[i][j] = z; }

    for (int kt = 0; kt < K / 32; ++kt) {
        const int k0 = kt * 32;
        __syncthreads();
#pragma unroll
        for (int i = 0; i < 16; ++i) {
            int idx = tid + i * 256;
            int r = idx >> 5, k = idx & 31;
            unsigned short v;
            if constexpr (MODE == 2) {
                v = Abf[(size_t)(m0 + r) * LDA + k0 + k];
            } else if constexpr (MODE == 1) {
                int g = gidx[m0 + r];
                v = f2bf(Af[(size_t)g * 256 + k0 + k]);
            } else {
                v = f2bf(Af[(size_t)(m0 + r) * LDA + k0 + k]);
            }
            As[r * 40 + k] = v;
        }
#pragma unroll
        for (int i = 0; i < 16; ++i) {
            int idx = tid + i * 256;
            int k = idx >> 7, c = idx & 127;
            Bs[c * 40 + k] = f2bf(Bp[(size_t)(k0 + k) * ldb + coff + c]);
        }
        __syncthreads();

        s16x8 af[4], bf[4];
#pragma unroll
        for (int i = 0; i < 4; ++i)
            af[i] = *(const s16x8*)&As[(wr * 64 + i * 16 + rsel) * 40 + k0f];
#pragma unroll
        for (int j = 0; j < 4; ++j)
            bf[j] = *(const s16x8*)&Bs[(wc * 64 + j * 16 + rsel) * 40 + k0f];
#pragma unroll
        for (int i = 0; i < 4; ++i)
#pragma unroll
            for (int j = 0; j < 4; ++j)
                acc[i][j] = __builtin_amdgcn_mfma_f32_16x16x32_bf16(af[i], bf[j], acc[i][j], 0, 0, 0);
    }

    // epilogue: row=(lane>>4)*4+reg, col=lane&15 within each 16x16 frag
    const int rg = (lane >> 4) * 4;
#pragma unroll
    for (int i = 0; i < 4; ++i)
#pragma unroll
        for (int j = 0; j < 4; ++j) {
            int row0 = m0 + wr * 64 + i * 16 + rg;
            int col  = n0 + wc * 64 + j * 16 + rsel;
            if constexpr (MODE == 0) {
                int sub = col >> 9;
                if (sub == 0) {
                    unsigned short* Ta = (unsigned short*)O0v;
#pragma unroll
                    for (int r = 0; r < 4; ++r)
                        Ta[(size_t)(row0 + r) * 512 + col] = f2bf(tanhf(acc[i][j][r] + e0[col]));
                } else {
                    int h = col & 511;
                    int bb = row0 >> 7, s0 = row0 & 127;   // s0 is 4-aligned
                    unsigned long long pk = 0;
#pragma unroll
                    for (int r = 0; r < 4; ++r)
                        pk |= (unsigned long long)f2bf(acc[i][j][r]) << (16 * r);
                    unsigned short* dstp = (sub == 1) ? (unsigned short*)O1v : (unsigned short*)O2v;
                    *(unsigned long long*)&dstp[(size_t)((bb * 512 + h) * 128 + s0)] = pk;
                }
            } else if constexpr (MODE == 1) {
                float* Of = (float*)O0v;
                float bias;
                if (col < 512) bias = e0[col] + e1[col] + e2[col];
                else { int h = col - 512; bias = e3[h] + e4[h] + e5[h]; }
#pragma unroll
                for (int r = 0; r < 4; ++r)
                    Of[(size_t)(row0 + r) * 1024 + col] = acc[i][j][r] + bias;
            } else {
                float* Of = (float*)O0v;
#pragma unroll
                for (int r = 0; r < 4; ++r)
                    Of[(size_t)(row0 + r) * 32000 + col] = acc[i][j][r] + 1.5f * e0[col];
            }
        }
}

// ---------------------------------------------------------------------------
// K3: persistent cooperative scan. 32 blocks x 1024 threads, 2 global
// barriers/step. Phase A: block j computes U[:, j*48..j*48+48) for ALL
// batches via MFMA with its 48-col weight slice resident in LDS (48 KB,
// loaded once). Phase BCD: block b handles batch b: tq -> scores (tanh
// identity on bf16 Ta) -> softmax -> ctx (bf16 transposed hW) -> update.
// ---------------------------------------------------------------------------
__global__ __launch_bounds__(1024) void scan_coop(
    const float* __restrict__ content, const float* __restrict__ sentiment,
    const float* __restrict__ b_prev,  const float* __restrict__ W_att,
    const unsigned short* __restrict__ Ta_bf,
    const unsigned short* __restrict__ hWcg_t,
    const unsigned short* __restrict__ hWc_t,
    const float* __restrict__ xgxs, const unsigned short* __restrict__ wfrag,
    unsigned short* __restrict__ S_bf, float* __restrict__ Ug,
    unsigned* __restrict__ ctr, unsigned short* __restrict__ dh)
{
    const int b = blockIdx.x;
    const int tid = threadIdx.x, lane = tid & 63, w = tid >> 6;

    __shared__ unsigned short W_lds[3 * 16 * 64 * 8];   // 48 KB, this block's col-slice
    __shared__ float tq[512];
    __shared__ float sc[128], al[128];
    __shared__ float s_f[512];
    __shared__ float cg[512], cs[512];

    // load weight slice once (ctiles [3b, 3b+3))
    {
        const s16x8* src = (const s16x8*)wfrag + (size_t)b * (3 * 16 * 64);
        s16x8* dst = (s16x8*)W_lds;
        for (int i = tid; i < 3 * 16 * 64; i += 1024) dst[i] = src[i];
    }
    float senth = 0.f, bprev_h = 0.f;
    if (tid < 512) {
        float v = content[b * 512 + tid];
        s_f[tid] = v;
        S_bf[b * 512 + tid] = f2bf(v);
        senth = 0.5f * sentiment[b * 512 + tid];
        bprev_h = b_prev[tid];
    }
    float wv[8];
    {
        const f32x4* wa = (const f32x4*)&W_att[lane * 8];
        f32x4 a0 = wa[0], a1 = wa[1];
#pragma unroll
        for (int j = 0; j < 4; ++j) { wv[j] = a0[j]; wv[4 + j] = a1[j]; }
    }
    const int kbase = (lane >> 4) * 8;

    gbar(ctr, 0, NB);    // S_bf (all batches) + W_lds ready

    for (int t = 0; t < 64; ++t) {
        // ---- Phase A: U[:, my 48 cols] = S @ Wslice (waves 0..5) ----
        if (w < 6) {
            const int mt = w & 1, ct = w >> 1;
            const int arow = mt * 16 + (lane & 15);
            f32x4 a4 = {0.f, 0.f, 0.f, 0.f};
            const s16x8* wl = (const s16x8*)W_lds;
#pragma unroll
            for (int kt = 0; kt < 16; ++kt) {
                s16x8 a = *(const s16x8*)&S_bf[arow * 512 + kt * 32 + kbase];
                s16x8 bfr = wl[(ct * 16 + kt) * 64 + lane];
                a4 = __builtin_amdgcn_mfma_f32_16x16x32_bf16(a, bfr, a4, 0, 0, 0);
            }
            const int cout = b * 48 + ct * 16 + (lane & 15);
            const int rbase = mt * 16 + (lane >> 4) * 4;
#pragma unroll
            for (int r = 0; r < 4; ++r)
                Ug[(rbase + r) * 1536 + cout] = a4[r];
        }
        gbar(ctr, 1 + 2 * t, NB);    // U ready

        // ---- Phase B: tq = tanh(q + b_prev) ----
        if (tid < 512) tq[tid] = tanhf(Ug[b * 1536 + tid] + bprev_h);
        __syncthreads();
        // scores via tanh(a+q) = (Ta+tq)/(1+Ta*tq); wave w -> positions w*8..+8
        {
            float tqv[8];
            {
                const f32x4* tp = (const f32x4*)&tq[lane * 8];
                f32x4 t0 = tp[0], t1 = tp[1];
#pragma unroll
                for (int j = 0; j < 4; ++j) { tqv[j] = t0[j]; tqv[4 + j] = t1[j]; }
            }
#pragma unroll
            for (int s8 = 0; s8 < 8; ++s8) {
                int s = w * 8 + s8;
                s16x8 tv = *(const s16x8*)&Ta_bf[((size_t)(b * 128 + s)) * 512 + lane * 8];
                float a = 0.f;
#pragma unroll
                for (int j = 0; j < 8; ++j) {
                    float ta = bf2f(tv[j]);
                    float num = ta + tqv[j];
                    float den = fmaf(ta, tqv[j], 1.0f);
                    a = fmaf(wv[j], num * __builtin_amdgcn_rcpf(den), a);
                }
#pragma unroll
                for (int off = 32; off; off >>= 1) a += __shfl_xor(a, off, 64);
                if (lane == 0) sc[s] = a;
            }
        }
        __syncthreads();
        // softmax over 128 (wave 0)
        if (w == 0) {
            float v0 = sc[lane], v1 = sc[lane + 64];
            float m = fmaxf(v0, v1);
#pragma unroll
            for (int off = 32; off; off >>= 1) m = fmaxf(m, __shfl_xor(m, off, 64));
            float p0 = __expf(v0 - m), p1 = __expf(v1 - m);
            float sm = p0 + p1;
#pragma unroll
            for (int off = 32; off; off >>= 1) sm += __shfl_xor(sm, off, 64);
            float inv = __builtin_amdgcn_rcpf(sm);
            al[lane] = p0 * inv; al[lane + 64] = p1 * inv;
        }
        __syncthreads();
        // ---- Phase C: ctx: thread = one h of one matrix; 16x contiguous b128
        {
            int mat = tid >> 9, h = tid & 511;
            const s16x8* Mp = (const s16x8*)((mat ? hWc_t : hWcg_t) + ((size_t)(b * 512 + h)) * 128);
            float a0 = 0.f, a1 = 0.f;
#pragma unroll
            for (int q = 0; q < 16; ++q) {
                s16x8 v = Mp[q];
#pragma unroll
                for (int j = 0; j < 8; j += 2) {
                    a0 = fmaf(al[q * 8 + j],     bf2f(v[j]),     a0);
                    a1 = fmaf(al[q * 8 + j + 1], bf2f(v[j + 1]), a1);
                }
            }
            if (mat) cs[h] = a0 + a1; else cg[h] = a0 + a1;
        }
        __syncthreads();
        // ---- Phase D: gate + state update ----
        if (tid < 512) {
            int h = tid;
            size_t row = (size_t)b * 64 + t;
            float g  = Ug[b * 1536 + 512 + h]  + xgxs[row * 1024 + h]       + cg[h];
            float r  = __builtin_amdgcn_rcpf(1.0f + __expf(-g));
            float sp = Ug[b * 1536 + 1024 + h] + xgxs[row * 1024 + 512 + h] + cs[h];
            float e  = __expf(2.0f * sp);
            float st = 1.0f - 2.0f * __builtin_amdgcn_rcpf(e + 1.0f);
            float sold = s_f[h];
            float ns = sold + r * (st - sold);
            s_f[h] = ns;
            S_bf[b * 512 + h] = f2bf(ns);
            dh[row * 512 + h] = f2bf(ns + senth);
        }
        gbar(ctr, 2 + 2 * t, NB);    // S_bf ready for next step's phase A
    }
}

// ---------------------------------------------------------------------------
extern "C" void kernel_launch(void* const* d_in, const int* in_sizes, int n_in,
                              void* d_out, int out_size, void* d_ws, size_t ws_size,
                              hipStream_t stream) {
    const float* content  = (const float*)d_in[0];
    const float* sentiment= (const float*)d_in[1];
    const float* hiddens  = (const float*)d_in[2];
    const int*   target   = (const int*)  d_in[3];
    const float* embed    = (const float*)d_in[4];
    const float* W_enc = (const float*)d_in[5];  const float* b_enc = (const float*)d_in[6];
    const float* W_prev= (const float*)d_in[7];  const float* b_prev= (const float*)d_in[8];
    const float* W_att = (const float*)d_in[9];  /* b_att (d_in[10]) cancels in softmax */
    const float* Wi_g  = (const float*)d_in[11]; const float* bi_g  = (const float*)d_in[12];
    const float* Wh_g  = (const float*)d_in[13]; const float* bh_g  = (const float*)d_in[14];
    const float* Wc_g  = (const float*)d_in[15]; const float* bc_g  = (const float*)d_in[16];
    const float* Wi    = (const float*)d_in[17]; const float* bi    = (const float*)d_in[18];
    const float* Wh    = (const float*)d_in[19]; const float* bh    = (const float*)d_in[20];
    const float* Wc    = (const float*)d_in[21]; const float* bc    = (const float*)d_in[22];
    const float* W_out = (const float*)d_in[23]; const float* b_out = (const float*)d_in[24];
    float* out = (float*)d_out;

    // workspace layout (bytes)
    char* ws = (char*)d_ws;
    unsigned short* wfrag = (unsigned short*)ws;                       // 1.5 MB @0
    unsigned* ctr   = (unsigned*)(ws + 0x180000);                      // 1 KB
    float* Ug       = (float*)(ws + 0x180400);                         // 192 KB [32][1536]
    unsigned short* Ta_bf   = (unsigned short*)(ws + 0x1B0400);        // 4 MB [4096][512]
    unsigned short* hWcg_t  = (unsigned short*)(ws + 0x5B0400);        // 4 MB [32][512][128]
    unsigned short* hWc_t   = (unsigned short*)(ws + 0x9B0400);        // 4 MB
    float* xgxs     = (float*)(ws + 0xDB0400);                         // 8 MB [2048][1024]
    unsigned short* dh      = (unsigned short*)(ws + 0x15B0400);       // 2 MB [2048][512]
    unsigned short* S_bf    = (unsigned short*)(ws + 0x17B0400);       // 32 KB [32][512]

    // zero barrier counters every launch (graph-capturable)
    hipMemsetAsync(ctr, 0, 1024, stream);

    // K0: pack recurrent weight fragments
    build_wfrag_k<<<96 * 16, 64, 0, stream>>>(W_prev, Wh_g, Wh, wfrag);

    // K1: PRE gemm -> Ta_bf (tanh, bf16), hWcg_t/hWc_t (bf16 transposed)
    gemm_mfma<0><<<32 * 12, 256, 0, stream>>>(
        hiddens, nullptr, nullptr, W_enc, Wc_g, Wc,
        b_enc, nullptr, nullptr, nullptr, nullptr, nullptr,
        (void*)Ta_bf, (void*)hWcg_t, (void*)hWc_t);

    // K2: XP gemm -> xgxs = [emb@Wi_g' + (bi_g+bh_g+bc_g)' | emb@Wi + (bi+bh+bc)]
    gemm_mfma<1><<<16 * 8, 256, 0, stream>>>(
        embed, nullptr, target, Wi_g, Wi, nullptr,
        bi_g, bh_g, bc_g, bi, bh, bc,
        (void*)xgxs, nullptr, nullptr);

    // K3: persistent scan -> dh
    scan_coop<<<NB, 1024, 0, stream>>>(
        content, sentiment, b_prev, W_att, Ta_bf, hWcg_t, hWc_t,
        xgxs, wfrag, S_bf, Ug, ctr, dh);

    // K4: OUT gemm -> d_out = dh@W_out + 1.5*b_out
    gemm_mfma<2><<<16 * 250, 256, 0, stream>>>(
        nullptr, dh, nullptr, W_out, nullptr, nullptr,
        b_out, nullptr, nullptr, nullptr, nullptr, nullptr,
        (void*)out, nullptr, nullptr);

    (void)in_sizes; (void)n_in; (void)out_size; (void)ws_size;
}

// Round 3
// 1552.602 us; speedup vs baseline: 2.9749x; 2.2007x over previous
//
#include <hip/hip_runtime.h>
#include <hip/hip_bf16.h>
#include <math.h>

// Problem dims
#define NB 32
#define NS 128
#define NT 64
#define NV 32000
#define NE 256
#define NH 512

typedef short s16x8 __attribute__((ext_vector_type(8)));
typedef float f32x4 __attribute__((ext_vector_type(4)));

__device__ __forceinline__ unsigned short f2bf(float x) {
    union { float f; unsigned u; } v; v.f = x;
    unsigned r = v.u + 0x7FFFu + ((v.u >> 16) & 1u);   // RNE
    return (unsigned short)(r >> 16);
}
__device__ __forceinline__ float bf2f(short h) {
    union { unsigned u; float f; } x;
    x.u = ((unsigned)(unsigned short)h) << 16;
    return x.f;
}

// ---------------------------------------------------------------------------
// Fence-free global barrier among 32 persistent blocks. NO agent fences (no
// L2 wb/inv cache-maintenance ops). Data crossing blocks travels exclusively
// through relaxed agent-scope atomics (coherent at the LLC by construction).
// Callers drain their atomic publishes with s_waitcnt vmcnt(0) per wave
// BEFORE arriving (hand-rolled release).
// ---------------------------------------------------------------------------
__device__ __forceinline__ void gbar(unsigned* c, int idx, unsigned nb) {
    __syncthreads();
    if (threadIdx.x == 0) {
        __hip_atomic_fetch_add(&c[idx], 1u, __ATOMIC_RELAXED, __HIP_MEMORY_SCOPE_AGENT);
        while (__hip_atomic_load(&c[idx], __ATOMIC_RELAXED, __HIP_MEMORY_SCOPE_AGENT) < nb)
            __builtin_amdgcn_s_sleep(1);
    }
    __syncthreads();
    asm volatile("" ::: "memory");   // compiler-only barrier (in-order HW issue)
}

// ---------------------------------------------------------------------------
// K0: pack W_s = [W_prev | Wh_g[:, :512] | Wh]  (512 x 1536) into MFMA
// B-fragment order: tile (ct,kt) holds B[k][c] for c=ct*16+(lane&15),
// k=kt*32+(lane>>4)*8+j.
// ---------------------------------------------------------------------------
__global__ void build_wfrag_k(const float* __restrict__ Wp,
                              const float* __restrict__ Whg,
                              const float* __restrict__ Wh,
                              unsigned short* __restrict__ wfrag) {
    int blk = blockIdx.x;            // = ct*16 + kt ; ct<96, kt<16
    int lane = threadIdx.x;
    int ct = blk >> 4, kt = blk & 15;
    int c = ct * 16 + (lane & 15);
    int kb = kt * 32 + (lane >> 4) * 8;
    s16x8 v;
#pragma unroll
    for (int j = 0; j < 8; ++j) {
        int k = kb + j;
        float x;
        if (c < 512)       x = Wp[k * 512 + c];
        else if (c < 1024) x = Whg[k * 1024 + (c - 512)];
        else               x = Wh[k * 512 + (c - 1024)];
        v[j] = (short)f2bf(x);
    }
    ((s16x8*)wfrag)[blk * 64 + lane] = v;
}

// ---------------------------------------------------------------------------
// Generic MFMA bf16 GEMM, 128x128 tile, BK=32, 4 waves (each 64x64 = 4x4 frags)
// MODE 0 (PRE): A=hiddens f32 [4096][1024]; B packed {W_enc|Wc_g[:, :512]|Wc};
//   epilogue: cols [0,512)->Ta_bf16[s][h]=tanh(v+b_enc); [512,1024)->hWcg_t
//   bf16 TRANSPOSED [b][h][s]; rest->hWc_t (same transposed layout).
// MODE 1 (XP):  A=embed rows gathered by target [2048][256]; B={Wi_g[:, :512]|Wi};
//   epilogue adds summed gate biases; out xgxs f32 [2048][1024]
// MODE 2 (OUT): A=dh bf16 [2048][512]; B=W_out [512][32000]; out = v + 1.5*b_out
// ---------------------------------------------------------------------------
template<int MODE>
__global__ __launch_bounds__(256, 2) void gemm_mfma(
    const float* __restrict__ Af, const unsigned short* __restrict__ Abf,
    const int* __restrict__ gidx,
    const float* __restrict__ B0, const float* __restrict__ B1, const float* __restrict__ B2,
    const float* __restrict__ e0, const float* __restrict__ e1, const float* __restrict__ e2,
    const float* __restrict__ e3, const float* __restrict__ e4, const float* __restrict__ e5,
    void* __restrict__ O0v, void* __restrict__ O1v, void* __restrict__ O2v)
{
    constexpr int M   = (MODE == 0) ? 4096 : 2048;
    constexpr int K   = (MODE == 0) ? 1024 : ((MODE == 1) ? 256 : 512);
    constexpr int LDA = (MODE == 0) ? 1024 : ((MODE == 1) ? 256 : 512);
    constexpr int MB  = M / 128;

    const int bm = blockIdx.x % MB, bn = blockIdx.x / MB;
    const int m0 = bm * 128, n0 = bn * 128;

    const float* Bp; int ldb, coff;
    if constexpr (MODE == 0) {
        int sub = n0 >> 9;
        Bp   = (sub == 0) ? B0 : (sub == 1) ? B1 : B2;
        ldb  = (sub == 1) ? 1024 : 512;
        coff = n0 & 511;
    } else if constexpr (MODE == 1) {
        if (n0 < 512) { Bp = B0; ldb = 1024; coff = n0; }
        else          { Bp = B1; ldb = 512;  coff = n0 - 512; }
    } else {
        Bp = B0; ldb = 32000; coff = n0;
    }

    __shared__ unsigned short As[128 * 40];
    __shared__ unsigned short Bs[128 * 40];

    const int tid = threadIdx.x, lane = tid & 63, w = tid >> 6;
    const int wr = w >> 1, wc = w & 1;
    const int k0f = (lane >> 4) * 8;
    const int rsel = lane & 15;

    f32x4 acc[4][4];
#pragma unroll
    for (int i = 0; i < 4; ++i)
#pragma unroll
        for (int j = 0; j < 4; ++j) { f32x4 z = {0.f, 0.f, 0.f, 0.f}; acc[i][j] = z; }

    for (int kt = 0; kt < K / 32; ++kt) {
        const int k0 = kt * 32;
        __syncthreads();
#pragma unroll
        for (int i = 0; i < 16; ++i) {
            int idx = tid + i * 256;
            int r = idx >> 5, k = idx & 31;
            unsigned short v;
            if constexpr (MODE == 2) {
                v = Abf[(size_t)(m0 + r) * LDA + k0 + k];
            } else if constexpr (MODE == 1) {
                int g = gidx[m0 + r];
                v = f2bf(Af[(size_t)g * 256 + k0 + k]);
            } else {
                v = f2bf(Af[(size_t)(m0 + r) * LDA + k0 + k]);
            }
            As[r * 40 + k] = v;
        }
#pragma unroll
        for (int i = 0; i < 16; ++i) {
            int idx = tid + i * 256;
            int k = idx >> 7, c = idx & 127;
            Bs[c * 40 + k] = f2bf(Bp[(size_t)(k0 + k) * ldb + coff + c]);
        }
        __syncthreads();

        s16x8 af[4], bf[4];
#pragma unroll
        for (int i = 0; i < 4; ++i)
            af[i] = *(const s16x8*)&As[(wr * 64 + i * 16 + rsel) * 40 + k0f];
#pragma unroll
        for (int j = 0; j < 4; ++j)
            bf[j] = *(const s16x8*)&Bs[(wc * 64 + j * 16 + rsel) * 40 + k0f];
#pragma unroll
        for (int i = 0; i < 4; ++i)
#pragma unroll
            for (int j = 0; j < 4; ++j)
                acc[i][j] = __builtin_amdgcn_mfma_f32_16x16x32_bf16(af[i], bf[j], acc[i][j], 0, 0, 0);
    }

    // epilogue: row=(lane>>4)*4+reg, col=lane&15 within each 16x16 frag
    const int rg = (lane >> 4) * 4;
#pragma unroll
    for (int i = 0; i < 4; ++i)
#pragma unroll
        for (int j = 0; j < 4; ++j) {
            int row0 = m0 + wr * 64 + i * 16 + rg;
            int col  = n0 + wc * 64 + j * 16 + rsel;
            if constexpr (MODE == 0) {
                int sub = col >> 9;
                if (sub == 0) {
                    unsigned short* Ta = (unsigned short*)O0v;
#pragma unroll
                    for (int r = 0; r < 4; ++r)
                        Ta[(size_t)(row0 + r) * 512 + col] = f2bf(tanhf(acc[i][j][r] + e0[col]));
                } else {
                    int h = col & 511;
                    int bb = row0 >> 7, s0 = row0 & 127;   // s0 is 4-aligned
                    unsigned long long pk = 0;
#pragma unroll
                    for (int r = 0; r < 4; ++r)
                        pk |= (unsigned long long)f2bf(acc[i][j][r]) << (16 * r);
                    unsigned short* dstp = (sub == 1) ? (unsigned short*)O1v : (unsigned short*)O2v;
                    *(unsigned long long*)&dstp[(size_t)((bb * 512 + h) * 128 + s0)] = pk;
                }
            } else if constexpr (MODE == 1) {
                float* Of = (float*)O0v;
                float bias;
                if (col < 512) bias = e0[col] + e1[col] + e2[col];
                else { int h = col - 512; bias = e3[h] + e4[h] + e5[h]; }
#pragma unroll
                for (int r = 0; r < 4; ++r)
                    Of[(size_t)(row0 + r) * 1024 + col] = acc[i][j][r] + bias;
            } else {
                float* Of = (float*)O0v;
#pragma unroll
                for (int r = 0; r < 4; ++r)
                    Of[(size_t)(row0 + r) * 32000 + col] = acc[i][j][r] + 1.5f * e0[col];
            }
        }
}

// ---------------------------------------------------------------------------
// K3: persistent cooperative scan, fence-free. 32 blocks x 1024 threads,
// 2 relaxed global barriers/step. Cross-block data (S: 32KB, U: 192KB/step)
// moves via relaxed agent-scope atomics only; big read-only arrays
// (wfrag/Ta/hW/xgxs) use normal cached loads and stay warm in L2.
// ---------------------------------------------------------------------------
__global__ __launch_bounds__(1024) void scan_coop(
    const float* __restrict__ content, const float* __restrict__ sentiment,
    const float* __restrict__ b_prev,  const float* __restrict__ W_att,
    const unsigned short* __restrict__ Ta_bf,
    const unsigned short* __restrict__ hWcg_t,
    const unsigned short* __restrict__ hWc_t,
    const float* __restrict__ xgxs, const unsigned short* __restrict__ wfrag,
    unsigned long long* __restrict__ S64, float* __restrict__ Ug,
    unsigned* __restrict__ ctr, unsigned short* __restrict__ dh)
{
    const int b = blockIdx.x;
    const int tid = threadIdx.x, lane = tid & 63, w = tid >> 6;

    __shared__ unsigned short W_lds[3 * 16 * 64 * 8];   // 48 KB, col-slice frags
    __shared__ unsigned short S_lds[32 * 512];          // 32 KB, all batches' state
    __shared__ float tq[512];
    __shared__ float sc[128], al[128];
    __shared__ float s_f[512];
    __shared__ unsigned short s_b[512];
    __shared__ float cg[512], cs[512];

    // load weight slice once (ctiles [3b, 3b+3))
    {
        const s16x8* src = (const s16x8*)wfrag + (size_t)b * (3 * 16 * 64);
        s16x8* dst = (s16x8*)W_lds;
        for (int i = tid; i < 3 * 16 * 64; i += 1024) dst[i] = src[i];
    }
    float senth = 0.f, bprev_h = 0.f;
    if (tid < 512) {
        float v = content[b * 512 + tid];
        s_f[tid] = v;
        s_b[tid] = f2bf(v);
        senth = 0.5f * sentiment[b * 512 + tid];
        bprev_h = b_prev[tid];
    }
    float wv[8];
    {
        const f32x4* wa = (const f32x4*)&W_att[lane * 8];
        f32x4 a0 = wa[0], a1 = wa[1];
#pragma unroll
        for (int j = 0; j < 4; ++j) { wv[j] = a0[j]; wv[4 + j] = a1[j]; }
    }
    const int kbase = (lane >> 4) * 8;

    __syncthreads();
    // publish initial state (u64-packed bf16 via relaxed agent atomics)
    if (tid < 128) {
        unsigned long long pk = *(const unsigned long long*)&s_b[tid * 4];
        __hip_atomic_store(&S64[b * 128 + tid], pk, __ATOMIC_RELAXED, __HIP_MEMORY_SCOPE_AGENT);
    }
    asm volatile("s_waitcnt vmcnt(0)" ::: "memory");
    gbar(ctr, 0, NB);

    for (int t = 0; t < 64; ++t) {
        // ---- Phase A: stage all-batch state to LDS (coherent loads) ----
#pragma unroll
        for (int ii = 0; ii < 4; ++ii) {
            int i = tid + ii * 1024;
            unsigned long long pk = __hip_atomic_load(&S64[i], __ATOMIC_RELAXED, __HIP_MEMORY_SCOPE_AGENT);
            *(unsigned long long*)&S_lds[i * 4] = pk;
        }
        __syncthreads();
        // U[:, my 48 cols] = S @ Wslice (waves 0..5)
        if (w < 6) {
            const int mt = w & 1, ct = w >> 1;
            const int arow = mt * 16 + (lane & 15);
            f32x4 a4 = {0.f, 0.f, 0.f, 0.f};
            const s16x8* wl = (const s16x8*)W_lds;
#pragma unroll
            for (int kt = 0; kt < 16; ++kt) {
                s16x8 a = *(const s16x8*)&S_lds[arow * 512 + kt * 32 + kbase];
                s16x8 bfr = wl[(ct * 16 + kt) * 64 + lane];
                a4 = __builtin_amdgcn_mfma_f32_16x16x32_bf16(a, bfr, a4, 0, 0, 0);
            }
            const int cout = b * 48 + ct * 16 + (lane & 15);
            const int rbase = mt * 16 + (lane >> 4) * 4;
#pragma unroll
            for (int r = 0; r < 4; ++r)
                __hip_atomic_store(&Ug[(rbase + r) * 1536 + cout], a4[r],
                                   __ATOMIC_RELAXED, __HIP_MEMORY_SCOPE_AGENT);
        }
        asm volatile("s_waitcnt vmcnt(0)" ::: "memory");
        gbar(ctr, 1 + 2 * t, NB);    // U ready

        // ---- Phase B: fetch my row of U; tq = tanh(q + b_prev) ----
        float guv = 0.f, suv = 0.f;
        if (tid < 512) {
            float qv = __hip_atomic_load(&Ug[b * 1536 + tid],        __ATOMIC_RELAXED, __HIP_MEMORY_SCOPE_AGENT);
            guv      = __hip_atomic_load(&Ug[b * 1536 + 512 + tid],  __ATOMIC_RELAXED, __HIP_MEMORY_SCOPE_AGENT);
            suv      = __hip_atomic_load(&Ug[b * 1536 + 1024 + tid], __ATOMIC_RELAXED, __HIP_MEMORY_SCOPE_AGENT);
            tq[tid] = tanhf(qv + bprev_h);
        }
        __syncthreads();
        // scores via tanh(a+q) = (Ta+tq)/(1+Ta*tq); wave w -> positions w*8..+8
        {
            float tqv[8];
            {
                const f32x4* tp = (const f32x4*)&tq[lane * 8];
                f32x4 t0 = tp[0], t1 = tp[1];
#pragma unroll
                for (int j = 0; j < 4; ++j) { tqv[j] = t0[j]; tqv[4 + j] = t1[j]; }
            }
#pragma unroll
            for (int s8 = 0; s8 < 8; ++s8) {
                int s = w * 8 + s8;
                s16x8 tv = *(const s16x8*)&Ta_bf[((size_t)(b * 128 + s)) * 512 + lane * 8];
                float a = 0.f;
#pragma unroll
                for (int j = 0; j < 8; ++j) {
                    float ta = bf2f(tv[j]);
                    float num = ta + tqv[j];
                    float den = fmaf(ta, tqv[j], 1.0f);
                    a = fmaf(wv[j], num * __builtin_amdgcn_rcpf(den), a);
                }
#pragma unroll
                for (int off = 32; off; off >>= 1) a += __shfl_xor(a, off, 64);
                if (lane == 0) sc[s] = a;
            }
        }
        __syncthreads();
        // softmax over 128 (wave 0)
        if (w == 0) {
            float v0 = sc[lane], v1 = sc[lane + 64];
            float m = fmaxf(v0, v1);
#pragma unroll
            for (int off = 32; off; off >>= 1) m = fmaxf(m, __shfl_xor(m, off, 64));
            float p0 = __expf(v0 - m), p1 = __expf(v1 - m);
            float sm = p0 + p1;
#pragma unroll
            for (int off = 32; off; off >>= 1) sm += __shfl_xor(sm, off, 64);
            float inv = __builtin_amdgcn_rcpf(sm);
            al[lane] = p0 * inv; al[lane + 64] = p1 * inv;
        }
        __syncthreads();
        // ---- Phase C: ctx: thread = one h of one matrix; 16x contiguous b128
        {
            int mat = tid >> 9, h = tid & 511;
            const s16x8* Mp = (const s16x8*)((mat ? hWc_t : hWcg_t) + ((size_t)(b * 512 + h)) * 128);
            float a0 = 0.f, a1 = 0.f;
#pragma unroll
            for (int q = 0; q < 16; ++q) {
                s16x8 v = Mp[q];
#pragma unroll
                for (int j = 0; j < 8; j += 2) {
                    a0 = fmaf(al[q * 8 + j],     bf2f(v[j]),     a0);
                    a1 = fmaf(al[q * 8 + j + 1], bf2f(v[j + 1]), a1);
                }
            }
            if (mat) cs[h] = a0 + a1; else cg[h] = a0 + a1;
        }
        __syncthreads();
        // ---- Phase D: gate + state update ----
        if (tid < 512) {
            int h = tid;
            size_t row = (size_t)b * 64 + t;
            float g  = guv + xgxs[row * 1024 + h]       + cg[h];
            float r  = __builtin_amdgcn_rcpf(1.0f + __expf(-g));
            float sp = suv + xgxs[row * 1024 + 512 + h] + cs[h];
            float e  = __expf(2.0f * sp);
            float st = 1.0f - 2.0f * __builtin_amdgcn_rcpf(e + 1.0f);
            float sold = s_f[h];
            float ns = sold + r * (st - sold);
            s_f[h] = ns;
            s_b[h] = f2bf(ns);
            dh[row * 512 + h] = f2bf(ns + senth);
        }
        __syncthreads();
        if (t < 63) {
            // publish new state
            if (tid < 128) {
                unsigned long long pk = *(const unsigned long long*)&s_b[tid * 4];
                __hip_atomic_store(&S64[b * 128 + tid], pk, __ATOMIC_RELAXED, __HIP_MEMORY_SCOPE_AGENT);
            }
            asm volatile("s_waitcnt vmcnt(0)" ::: "memory");
            gbar(ctr, 2 + 2 * t, NB);    // S ready for next step's Phase A
        }
    }
}

// ---------------------------------------------------------------------------
extern "C" void kernel_launch(void* const* d_in, const int* in_sizes, int n_in,
                              void* d_out, int out_size, void* d_ws, size_t ws_size,
                              hipStream_t stream) {
    const float* content  = (const float*)d_in[0];
    const float* sentiment= (const float*)d_in[1];
    const float* hiddens  = (const float*)d_in[2];
    const int*   target   = (const int*)  d_in[3];
    const float* embed    = (const float*)d_in[4];
    const float* W_enc = (const float*)d_in[5];  const float* b_enc = (const float*)d_in[6];
    const float* W_prev= (const float*)d_in[7];  const float* b_prev= (const float*)d_in[8];
    const float* W_att = (const float*)d_in[9];  /* b_att (d_in[10]) cancels in softmax */
    const float* Wi_g  = (const float*)d_in[11]; const float* bi_g  = (const float*)d_in[12];
    const float* Wh_g  = (const float*)d_in[13]; const float* bh_g  = (const float*)d_in[14];
    const float* Wc_g  = (const float*)d_in[15]; const float* bc_g  = (const float*)d_in[16];
    const float* Wi    = (const float*)d_in[17]; const float* bi    = (const float*)d_in[18];
    const float* Wh    = (const float*)d_in[19]; const float* bh    = (const float*)d_in[20];
    const float* Wc    = (const float*)d_in[21]; const float* bc    = (const float*)d_in[22];
    const float* W_out = (const float*)d_in[23]; const float* b_out = (const float*)d_in[24];
    float* out = (float*)d_out;

    // workspace layout (bytes)
    char* ws = (char*)d_ws;
    unsigned short* wfrag = (unsigned short*)ws;                       // 1.5 MB @0
    unsigned* ctr   = (unsigned*)(ws + 0x180000);                      // 1 KB
    float* Ug       = (float*)(ws + 0x180400);                         // 192 KB [32][1536]
    unsigned short* Ta_bf   = (unsigned short*)(ws + 0x1B0400);        // 4 MB [4096][512]
    unsigned short* hWcg_t  = (unsigned short*)(ws + 0x5B0400);        // 4 MB [32][512][128]
    unsigned short* hWc_t   = (unsigned short*)(ws + 0x9B0400);        // 4 MB
    float* xgxs     = (float*)(ws + 0xDB0400);                         // 8 MB [2048][1024]
    unsigned short* dh      = (unsigned short*)(ws + 0x15B0400);       // 2 MB [2048][512]
    unsigned long long* S64 = (unsigned long long*)(ws + 0x17B0400);   // 32 KB [32][128] u64

    // zero barrier counters every launch (graph-capturable)
    hipMemsetAsync(ctr, 0, 1024, stream);

    // K0: pack recurrent weight fragments
    build_wfrag_k<<<96 * 16, 64, 0, stream>>>(W_prev, Wh_g, Wh, wfrag);

    // K1: PRE gemm -> Ta_bf (tanh, bf16), hWcg_t/hWc_t (bf16 transposed)
    gemm_mfma<0><<<32 * 12, 256, 0, stream>>>(
        hiddens, nullptr, nullptr, W_enc, Wc_g, Wc,
        b_enc, nullptr, nullptr, nullptr, nullptr, nullptr,
        (void*)Ta_bf, (void*)hWcg_t, (void*)hWc_t);

    // K2: XP gemm -> xgxs = [emb@Wi_g' + (bi_g+bh_g+bc_g)' | emb@Wi + (bi+bh+bc)]
    gemm_mfma<1><<<16 * 8, 256, 0, stream>>>(
        embed, nullptr, target, Wi_g, Wi, nullptr,
        bi_g, bh_g, bc_g, bi, bh, bc,
        (void*)xgxs, nullptr, nullptr);

    // K3: persistent scan -> dh
    scan_coop<<<NB, 1024, 0, stream>>>(
        content, sentiment, b_prev, W_att, Ta_bf, hWcg_t, hWc_t,
        xgxs, wfrag, S64, Ug, ctr, dh);

    // K4: OUT gemm -> d_out = dh@W_out + 1.5*b_out
    gemm_mfma<2><<<16 * 250, 256, 0, stream>>>(
        nullptr, dh, nullptr, W_out, nullptr, nullptr,
        b_out, nullptr, nullptr, nullptr, nullptr, nullptr,
        (void*)out, nullptr, nullptr);

    (void)in_sizes; (void)n_in; (void)out_size; (void)ws_size;
}